// Round 5
// baseline (389.671 us; speedup 1.0000x reference)
//
#include <hip/hip_runtime.h>
#include <cstdint>

typedef __attribute__((ext_vector_type(8))) short bf16x8;
typedef __attribute__((ext_vector_type(4))) float f32x4;

__device__ __forceinline__ unsigned short f2bf(float v) {
  unsigned u = __builtin_bit_cast(unsigned, v);
  u += 0x7FFFu + ((u >> 16) & 1u);   // RNE
  return (unsigned short)(u >> 16);
}

// async global->LDS, 16B per lane; LDS dest = wave-uniform base + lane*16
__device__ __forceinline__ void gload16(const unsigned short* g, unsigned short* l) {
  __builtin_amdgcn_global_load_lds(
      (const __attribute__((address_space(1))) void*)(uintptr_t)g,
      (__attribute__((address_space(3))) void*)(uint32_t)(uintptr_t)l,
      16, 0, 0);
}

// Inline-asm ds_read_b128 (outside compiler waitcnt bookkeeping; we count).
__device__ __forceinline__ bf16x8 ds_read128(const unsigned short* p) {
  bf16x8 r;
  asm volatile("ds_read_b128 %0, %1"
               : "=v"(r)
               : "v"((uint32_t)(uintptr_t)p));
  return r;
}

#define BAR()    asm volatile("s_barrier" ::: "memory")
// counted lgkm waits; sched_barrier(0) pins MFMAs below the wait (rule #18)
#define LGKMW(N) do { asm volatile("s_waitcnt lgkmcnt(" #N ")" ::: "memory"); \
                      __builtin_amdgcn_sched_barrier(0); } while (0)
#define VMW(N)   asm volatile("s_waitcnt vmcnt(" #N ")" ::: "memory")

// Pipelined bf16 NT GEMM core: C[256x256] += A[256xK] * B[256xK]^T, BK=64.
// 512 threads = 8 waves (2M x 4N); per-wave 128x64 output, acc[8][4].
//
// LDS: 8 half-tile slots x 16 KiB (128 KiB), bank b=(t&1): slots b*4 +
// {0:B0,1:B1,2:A0,3:A1}. Half = 128 rows x 64 bf16, XOR-swizzled 16B chunks
// (logical chunk c of row r at physical c^(r&7)) -> conflict-free
// ds_read_b128; staging lane-contiguous with pre-swizzled global source.
//
// KEY CHANGE vs r2/r3 (which sat at 19% MfmaUtil): ONE-PHASE-AHEAD REGISTER
// PIPELINE. Phase p issues the ds_reads for phase p+1's MFMA, then runs
// phase p's MFMAs on registers loaded during phase p-1. The counted
// lgkmcnt(4|12) waits only for the PREVIOUS phase's reads, leaving this
// phase's in flight -> DS pipe drains UNDER the MFMA cluster instead of
// strictly alternating with it (r2/r3 serialized the two pipes by putting
// read and consumer in the same barrier interval).
//
// Phase schedule per tile t (16 MFMA each; acc rows 2p,2p+1 at phase p):
//  ph0: read A frags 2,3      ; stage A0(t+1)
//  ph1: read A frags 4,5      ; stage A1(t+1)
//  ph2: read A frags 6,7      ; stage B0(t+2)
//  ph3: vmcnt(2) [forces B(t+1),A(t+1) landed; leaves B0(t+2) in flight];
//       read tile t+1: A frags 0,1 + all B (12 reads); stage B1(t+2)
//  each phase: reads; stage; BAR; lgkmcnt(4|12); 16 MFMA; rotate regs.
// vmcnt audit (per wave, steady state): entering tile t, outstanding =
// B(t+1)=4. ph0 +2 ->6, ph1 ->8, ph2 ->10; at ph3's VMW(2): 10 outstanding,
// <=2 completes the 8 oldest = B(t+1)+A(t+1), exactly what tile t+1 reads
// need. t==NT-2: nothing staged at ph2 -> 8 outstanding, VMW(0) drains.
// Slot overwrite discipline unchanged from refcheck'd r2/r3 (>=2 barriers
// between a slot's last read-issue and its overwrite-issue).
__device__ __forceinline__ void gemm_core(
    const unsigned short* __restrict__ A, const unsigned short* __restrict__ B,
    int lda, int ldb, int NT,
    unsigned short* lds, f32x4 acc[8][4])
{
  const int tid  = threadIdx.x;
  const int w    = tid >> 6;
  const int lane = tid & 63;
  const int wr   = w >> 2;        // 0..1  (M)
  const int wc   = w & 3;         // 0..3  (N)
  const int lrow = lane & 15;
  const int kq   = lane >> 4;

  const int srow = tid >> 3;                        // 0..63
  const int schk = ((tid & 7) ^ (srow & 7)) * 8;    // pre-swizzled source chunk
  const unsigned short* gA = A + (long)srow * lda + schk;
  const unsigned short* gB = B + (long)srow * ldb + schk;
  unsigned short* const stg = lds + w * 512;        // + slot*8192 (+4096)

  const int pc0 = ((0 + kq) ^ (lrow & 7)) * 8;      // k-step 0 physical chunk
  const int pc1 = ((4 + kq) ^ (lrow & 7)) * 8;      // k-step 1 physical chunk

  #define STG(g, ld, H, t, s) do { \
    gload16((g) + (long)(H)      * (ld) + (t) * 64, stg + (s) * 8192); \
    gload16((g) + (long)((H)+64) * (ld) + (t) * 64, stg + (s) * 8192 + 4096); \
  } while (0)

  // prologue: stage halves of tile 0 and B of tile 1 (12 vm ops/wave)
  STG(gB, ldb, 0,   0, 0);   // B0(0)
  STG(gB, ldb, 128, 0, 1);   // B1(0)
  STG(gA, lda, 0,   0, 2);   // A0(0)
  STG(gA, lda, 128, 0, 3);   // A1(0)
  STG(gB, ldb, 0,   1, 4);   // B0(1)
  STG(gB, ldb, 128, 1, 5);   // B1(1)
  VMW(4);                    // tile 0's 8 ops landed; B(1)'s 4 in flight
  BAR();

  bf16x8 afc[2][2], afn[2][2], bc[4][2], bn[4][2];
  {
    // prologue reads: tile 0 phase-0 operands (12 reads, counted by ph0's lgkm)
    const unsigned short* lA0 = lds + (2 + wr) * 8192 + lrow * 64;
    const unsigned short* lB0 = lds + (wc >> 1) * 8192 + ((wc & 1) * 64 + lrow) * 64;
#pragma unroll
    for (int j = 0; j < 4; ++j) {
      bc[j][0] = ds_read128(lB0 + j * 1024 + pc0);
      bc[j][1] = ds_read128(lB0 + j * 1024 + pc1);
    }
#pragma unroll
    for (int i = 0; i < 2; ++i) {
      afc[i][0] = ds_read128(lA0 + i * 1024 + pc0);
      afc[i][1] = ds_read128(lA0 + i * 1024 + pc1);
    }
  }

  for (int t = 0; t < NT; ++t) {
    const unsigned short* lA  = lds + (t & 1) * 32768 + (2 + wr) * 8192 + lrow * 64;
    const unsigned short* lAn = lds + ((t + 1) & 1) * 32768 + (2 + wr) * 8192 + lrow * 64;
    const unsigned short* lBn = lds + ((t + 1) & 1) * 32768 + (wc >> 1) * 8192 + ((wc & 1) * 64 + lrow) * 64;
    const bool doA  = (t + 1 < NT);
    const bool doB  = (t + 2 < NT);
    const bool last = (t == NT - 1);

#pragma unroll
    for (int p = 0; p < 4; ++p) {
      // 1) issue NEXT phase's fragment reads
      if (p < 3) {
#pragma unroll
        for (int i = 0; i < 2; ++i) {
          afn[i][0] = ds_read128(lA + (2 * (p + 1) + i) * 1024 + pc0);
          afn[i][1] = ds_read128(lA + (2 * (p + 1) + i) * 1024 + pc1);
        }
      } else if (!last) {
        if (t == NT - 2) { VMW(0); } else { VMW(2); }  // tile t+1 fully landed
#pragma unroll
        for (int i = 0; i < 2; ++i) {
          afn[i][0] = ds_read128(lAn + i * 1024 + pc0);
          afn[i][1] = ds_read128(lAn + i * 1024 + pc1);
        }
#pragma unroll
        for (int j = 0; j < 4; ++j) {
          bn[j][0] = ds_read128(lBn + j * 1024 + pc0);
          bn[j][1] = ds_read128(lBn + j * 1024 + pc1);
        }
      }
      // 2) staging (global->LDS, vmcnt-only)
      if (p == 0 && doA) STG(gA, lda, 0,   t + 1, ((t + 1) & 1) * 4 + 2);
      if (p == 1 && doA) STG(gA, lda, 128, t + 1, ((t + 1) & 1) * 4 + 3);
      if (p == 2 && doB) STG(gB, ldb, 0,   t + 2, (t & 1) * 4 + 0);
      if (p == 3 && doB) STG(gB, ldb, 128, t + 2, (t & 1) * 4 + 1);
      // 3) one barrier per phase
      BAR();
      // 4) counted lgkm: previous phase's reads done; this phase's stay in flight
      if (p == 3) { if (last) { LGKMW(0); } else { LGKMW(12); } }
      else       { LGKMW(4); }
      // 5) MFMA on registers loaded LAST phase
      __builtin_amdgcn_s_setprio(1);
#pragma unroll
      for (int i = 0; i < 2; ++i)
#pragma unroll
        for (int j = 0; j < 4; ++j) {
          acc[2 * p + i][j] = __builtin_amdgcn_mfma_f32_16x16x32_bf16(afc[i][0], bc[j][0], acc[2 * p + i][j], 0, 0, 0);
          acc[2 * p + i][j] = __builtin_amdgcn_mfma_f32_16x16x32_bf16(afc[i][1], bc[j][1], acc[2 * p + i][j], 0, 0, 0);
        }
      __builtin_amdgcn_s_setprio(0);
      // 6) rotate (compile-time indices; compiler renames, no real movs)
      if (p < 3 || !last) {
#pragma unroll
        for (int i = 0; i < 2; ++i) { afc[i][0] = afn[i][0]; afc[i][1] = afn[i][1]; }
      }
      if (p == 3 && !last) {
#pragma unroll
        for (int j = 0; j < 4; ++j) { bc[j][0] = bn[j][0]; bc[j][1] = bn[j][1]; }
      }
    }
  }
  #undef STG
}

// QKV projection: x[8192,1024] * W[1024,1024]^T + b, fused over Q/K/V.
// blockIdx.y = sel*4 + nb. Q,K row-major bf16; V transposed per batch.
__global__ __launch_bounds__(512, 2) void gemm_qkv(
    const unsigned short* __restrict__ xh,
    const unsigned short* __restrict__ wh,
    const float* __restrict__ bq, const float* __restrict__ bk, const float* __restrict__ bv,
    unsigned short* __restrict__ Qh, unsigned short* __restrict__ Kh,
    unsigned short* __restrict__ Vth)
{
  __shared__ __align__(16) unsigned short lds[65536];   // 128 KiB
  const int Mblk = blockIdx.x * 256;
  const int sel  = blockIdx.y >> 2;   // 0=Q 1=K 2=V
  const int nb   = blockIdx.y & 3;    // 256-wide col block within 1024

  const unsigned short* A = xh + (long)Mblk * 1024;
  const unsigned short* B = wh + sel * 1048576 + (long)(nb * 256) * 1024;
  const float* bias = (sel == 0) ? bq : (sel == 1) ? bk : bv;

  f32x4 acc[8][4] = {};
  gemm_core(A, B, 1024, 1024, 16, lds, acc);

  const int lane = threadIdx.x & 63, w = threadIdx.x >> 6;
  const int wr = w >> 2, wc = w & 3;
  const int lrow = lane & 15, kq = lane >> 4;

#pragma unroll
  for (int i = 0; i < 8; ++i) {
#pragma unroll
    for (int j = 0; j < 4; ++j) {
      const int col = nb * 256 + wc * 64 + j * 16 + lrow;   // output feature d
      const float bsv = bias[col];
#pragma unroll
      for (int r = 0; r < 4; ++r) {
        const int tok = Mblk + wr * 128 + i * 16 + kq * 4 + r;  // token index
        const unsigned short h = f2bf(acc[i][j][r] + bsv);
        if (sel == 2) {
          Vth[(long)(tok >> 11) * 2097152 + (long)col * 2048 + (tok & 2047)] = h;
        } else if (sel == 0) {
          Qh[(long)tok * 1024 + col] = h;
        } else {
          Kh[(long)tok * 1024 + col] = h;
        }
      }
    }
  }
}

// Batched NT GEMM, fp32 out: C[z] = alpha * A[z] * B[z]^T  (tile 256x256)
__global__ __launch_bounds__(512, 2) void gemm_f32out(
    const unsigned short* __restrict__ A, const unsigned short* __restrict__ B,
    int lda, int ldb, int NT,
    long sA, long sB, float* __restrict__ C, int ldc, long sC, float alpha)
{
  __shared__ __align__(16) unsigned short lds[65536];   // 128 KiB
  const int Mblk = blockIdx.x * 256;
  const int Nblk = blockIdx.y * 256;
  const long z = blockIdx.z;
  const unsigned short* Ab = A + z * sA + (long)Mblk * lda;
  const unsigned short* Bb = B + z * sB + (long)Nblk * ldb;
  float* Cb = C + z * sC;

  f32x4 acc[8][4] = {};
  gemm_core(Ab, Bb, lda, ldb, NT, lds, acc);

  const int lane = threadIdx.x & 63, w = threadIdx.x >> 6;
  const int wr = w >> 2, wc = w & 3;
  const int lrow = lane & 15, kq = lane >> 4;
#pragma unroll
  for (int i = 0; i < 8; ++i)
#pragma unroll
    for (int j = 0; j < 4; ++j)
#pragma unroll
      for (int r = 0; r < 4; ++r) {
        const int row = Mblk + wr * 128 + i * 16 + kq * 4 + r;
        const int col = Nblk + wc * 64 + j * 16 + lrow;
        Cb[(long)row * ldc + col] = alpha * acc[i][j][r];
      }
}

// Row softmax over 2048 entries, in place (fp32) + bf16 copy for the PV GEMM.
__global__ __launch_bounds__(256) void softmax_rows(
    float* __restrict__ S, unsigned short* __restrict__ Ph)
{
  __shared__ float red[4];
  const long row = blockIdx.x;
  float* rp = S + row * 2048;
  const int t = threadIdx.x;

  float x[8];
  *(float4*)&x[0] = reinterpret_cast<const float4*>(rp)[t];
  *(float4*)&x[4] = reinterpret_cast<const float4*>(rp)[t + 256];

  float m = x[0];
#pragma unroll
  for (int i = 1; i < 8; ++i) m = fmaxf(m, x[i]);
  for (int o = 32; o; o >>= 1) m = fmaxf(m, __shfl_xor(m, o, 64));
  if ((t & 63) == 0) red[t >> 6] = m;
  __syncthreads();
  m = fmaxf(fmaxf(red[0], red[1]), fmaxf(red[2], red[3]));
  __syncthreads();

  float s = 0.f;
#pragma unroll
  for (int i = 0; i < 8; ++i) { x[i] = expf(x[i] - m); s += x[i]; }
  for (int o = 32; o; o >>= 1) s += __shfl_xor(s, o, 64);
  if ((t & 63) == 0) red[t >> 6] = s;
  __syncthreads();
  s = (red[0] + red[1]) + (red[2] + red[3]);
  const float inv = 1.0f / s;

#pragma unroll
  for (int i = 0; i < 8; ++i) x[i] *= inv;
  reinterpret_cast<float4*>(rp)[t]       = *(float4*)&x[0];
  reinterpret_cast<float4*>(rp)[t + 256] = *(float4*)&x[4];

  const long b0 = row * 2048 + t * 4;
#pragma unroll
  for (int k = 0; k < 4; ++k) Ph[b0 + k] = f2bf(x[k]);
  const long b1 = row * 2048 + 1024 + t * 4;
#pragma unroll
  for (int k = 0; k < 4; ++k) Ph[b1 + k] = f2bf(x[4 + k]);
}

// One fused cast pass: x (2,097,152 float4) then Wq|Wk|Wv (262,144 float4 each).
__global__ __launch_bounds__(256) void to_bf16_all(
    const float* __restrict__ x,
    const float* __restrict__ Wq, const float* __restrict__ Wk,
    const float* __restrict__ Wv,
    unsigned short* __restrict__ xh, unsigned short* __restrict__ wh)
{
  const int stride = gridDim.x * 256;
  for (int i = blockIdx.x * 256 + threadIdx.x; i < 2883584; i += stride) {
    const float* src; unsigned short* dst; int off;
    if (i < 2097152)      { src = x;  dst = xh; off = i; }
    else {
      const int j = i - 2097152;
      const int sel = j >> 18;          // 0..2 (262144 float4 per W)
      off = j & 262143;
      src = (sel == 0) ? Wq : (sel == 1) ? Wk : Wv;
      dst = wh + (long)sel * 1048576;
    }
    const float4 v = reinterpret_cast<const float4*>(src)[off];
    ushort4 h;
    h.x = f2bf(v.x); h.y = f2bf(v.y); h.z = f2bf(v.z); h.w = f2bf(v.w);
    reinterpret_cast<ushort4*>(dst)[off] = h;
  }
}

extern "C" void kernel_launch(void* const* d_in, const int* in_sizes, int n_in,
                              void* d_out, int out_size, void* d_ws, size_t ws_size,
                              hipStream_t stream)
{
  const float* x  = (const float*)d_in[0];
  const float* Wq = (const float*)d_in[1];
  const float* bq = (const float*)d_in[2];
  const float* Wk = (const float*)d_in[3];
  const float* bk = (const float*)d_in[4];
  const float* Wv = (const float*)d_in[5];
  const float* bv = (const float*)d_in[6];

  float* out  = (float*)d_out;                 // [4,2048,1024]
  float* attn = (float*)d_out + 8388608;       // [4,2048,2048]

  unsigned short* ws  = (unsigned short*)d_ws;
  unsigned short* xh  = ws;                    //  8,388,608
  unsigned short* wh  = xh + 8388608;          //  3,145,728 (Wq|Wk|Wv)
  unsigned short* Qh  = wh + 3145728;          //  8,388,608
  unsigned short* Kh  = Qh + 8388608;          //  8,388,608
  unsigned short* Vth = Kh + 8388608;          //  8,388,608  Vt[b][d][m]
  unsigned short* Ph  = Vth + 8388608;         // 16,777,216  P bf16

  to_bf16_all<<<2048, 256, 0, stream>>>(x, Wq, Wk, Wv, xh, wh);

  // Q,K,V projections (M=8192, N=3x1024, K=1024): 384 blocks, default dispatch
  gemm_qkv<<<dim3(32, 12), 512, 0, stream>>>(xh, wh, bq, bk, bv, Qh, Kh, Vth);

  // scores = Q K^T / 32 -> fp32 into d_out's attention slot: 256 blocks
  gemm_f32out<<<dim3(8, 8, 4), 512, 0, stream>>>(Qh, Kh, 1024, 1024, 16,
      2097152L, 2097152L, attn, 2048, 4194304L, 0.03125f);

  // softmax rows in place + emit P bf16
  softmax_rows<<<8192, 256, 0, stream>>>(attn, Ph);

  // out = P * Vt^T (K=2048 -> NT=32): 128 blocks
  gemm_f32out<<<dim3(8, 4, 4), 512, 0, stream>>>(Ph, Vth, 2048, 2048, 32,
      4194304L, 2097152L, out, 1024, 2097152L, 1.0f);
}

// Round 6
// 300.106 us; speedup vs baseline: 1.2984x; 1.2984x over previous
//
#include <hip/hip_runtime.h>
#include <cstdint>

typedef __attribute__((ext_vector_type(8))) short bf16x8;
typedef __attribute__((ext_vector_type(4))) float f32x4;

__device__ __forceinline__ unsigned short f2bf(float v) {
  unsigned u = __builtin_bit_cast(unsigned, v);
  u += 0x7FFFu + ((u >> 16) & 1u);   // RNE
  return (unsigned short)(u >> 16);
}

// async global->LDS, 16B per lane; LDS dest = wave-uniform base + lane*16
__device__ __forceinline__ void gload16(const unsigned short* g, unsigned short* l) {
  __builtin_amdgcn_global_load_lds(
      (const __attribute__((address_space(1))) void*)(uintptr_t)g,
      (__attribute__((address_space(3))) void*)(uint32_t)(uintptr_t)l,
      16, 0, 0);
}

// Single-pass bf16 NT GEMM core: C[128x128] += A[128xK] * B[128xK]^T, BK=64.
// (r0-proven structure: 2x __syncthreads per K-tile, 256 thr / 4 waves,
//  32 KiB LDS -> 4-5 blocks/CU of TLP hides the staging drain. Three
//  pipelined 256^2 variants (r1-r3, r5) all regressed to ~100us/20% MfmaUtil;
//  this structure at 741 TF is the session's verified best.)
// LDS tile 128 rows x 64 shorts; XOR swizzle: row r's logical 16B chunk c at
// physical c ^ (r&7) -> conflict-free ds_read_b128, lane-contiguous staging.
__device__ __forceinline__ void gemm_core(
    const unsigned short* __restrict__ A, const unsigned short* __restrict__ B,
    int lda, int ldb, int K,
    unsigned short* ldsA, unsigned short* ldsB, f32x4 acc[4][4])
{
  const int tid  = threadIdx.x;
  const int wave = tid >> 6;
  const int lane = tid & 63;
  const int wm = (wave >> 1) * 64;
  const int wn = (wave & 1) * 64;
  const int lrow = lane & 15;
  const int kq = lane >> 4;

  // staging: wave w fills rows [w*32, w*32+32); lane covers row w*32+i*8+(lane>>3),
  // swizzled chunk (lane&7)^((lane>>3)&7); 4 calls per operand per K-chunk.
  const int sr = lane >> 3;                       // 0..7
  const int sc = (lane & 7) ^ (sr & 7);           // swizzled source chunk
  const unsigned short* ga = A + (long)(wave * 32 + sr) * lda + sc * 8;
  const unsigned short* gb = B + (long)(wave * 32 + sr) * ldb + sc * 8;
  unsigned short* lA = ldsA + wave * 2048;        // 4 KB slice per wave
  unsigned short* lB = ldsB + wave * 2048;

  const int pc0 = ((0 * 4 + kq) ^ (lrow & 7)) * 8;   // k-step 0 read chunk
  const int pc1 = ((1 * 4 + kq) ^ (lrow & 7)) * 8;   // k-step 1 read chunk

#pragma unroll 1
  for (int kb = 0; kb < K; kb += 64) {
    __syncthreads();  // previous tile fully consumed
#pragma unroll
    for (int i = 0; i < 4; ++i) {
      gload16(ga + kb + (long)i * 8 * lda, lA + i * 512);
      gload16(gb + kb + (long)i * 8 * ldb, lB + i * 512);
    }
    __syncthreads();  // drains vmcnt -> LDS valid

    bf16x8 af[4], bfr[4];
    // k-step 0 (k = kb .. kb+31)
#pragma unroll
    for (int i = 0; i < 4; ++i)
      af[i] = *(const bf16x8*)(ldsA + (wm + i * 16 + lrow) * 64 + pc0);
#pragma unroll
    for (int j = 0; j < 4; ++j)
      bfr[j] = *(const bf16x8*)(ldsB + (wn + j * 16 + lrow) * 64 + pc0);
#pragma unroll
    for (int i = 0; i < 4; ++i)
#pragma unroll
      for (int j = 0; j < 4; ++j)
        acc[i][j] = __builtin_amdgcn_mfma_f32_16x16x32_bf16(af[i], bfr[j], acc[i][j], 0, 0, 0);

    // k-step 1 (k = kb+32 .. kb+63)
#pragma unroll
    for (int i = 0; i < 4; ++i)
      af[i] = *(const bf16x8*)(ldsA + (wm + i * 16 + lrow) * 64 + pc1);
#pragma unroll
    for (int j = 0; j < 4; ++j)
      bfr[j] = *(const bf16x8*)(ldsB + (wn + j * 16 + lrow) * 64 + pc1);
#pragma unroll
    for (int i = 0; i < 4; ++i)
#pragma unroll
      for (int j = 0; j < 4; ++j)
        acc[i][j] = __builtin_amdgcn_mfma_f32_16x16x32_bf16(af[i], bfr[j], acc[i][j], 0, 0, 0);
  }
}

// QKV projection: x[8192,1024] * W[1024,1024]^T + b, fused over Q/K/V via blockIdx.y.
// Q,K stored row-major bf16; V stored transposed per batch: Vt[b][d][m].
__global__ __launch_bounds__(256, 4) void gemm_qkv(
    const unsigned short* __restrict__ xh,
    const unsigned short* __restrict__ wh,
    const float* __restrict__ bq, const float* __restrict__ bk, const float* __restrict__ bv,
    unsigned short* __restrict__ Qh, unsigned short* __restrict__ Kh,
    unsigned short* __restrict__ Vth)
{
  __shared__ __align__(16) unsigned short ldsA[8192];
  __shared__ __align__(16) unsigned short ldsB[8192];
  const int Mblk = blockIdx.x * 128;
  const int sel  = blockIdx.y >> 3;   // 0=Q 1=K 2=V
  const int nb   = blockIdx.y & 7;    // 128-wide col block within 1024

  const unsigned short* A = xh + (long)Mblk * 1024;
  const unsigned short* B = wh + sel * 1048576 + (long)(nb * 128) * 1024;
  const float* bias = (sel == 0) ? bq : (sel == 1) ? bk : bv;

  f32x4 acc[4][4] = {};
  gemm_core(A, B, 1024, 1024, 1024, ldsA, ldsB, acc);

  const int lane = threadIdx.x & 63, wave = threadIdx.x >> 6;
  const int wm = (wave >> 1) * 64, wn = (wave & 1) * 64;
  const int lrow = lane & 15, kq = lane >> 4;

#pragma unroll
  for (int i = 0; i < 4; ++i) {
#pragma unroll
    for (int j = 0; j < 4; ++j) {
      const int col = nb * 128 + wn + j * 16 + lrow;   // output feature d
      const float bsv = bias[col];
#pragma unroll
      for (int r = 0; r < 4; ++r) {
        const int tok = Mblk + wm + i * 16 + kq * 4 + r;  // token index
        const unsigned short h = f2bf(acc[i][j][r] + bsv);
        if (sel == 2) {
          Vth[(long)(tok >> 11) * 2097152 + (long)col * 2048 + (tok & 2047)] = h;
        } else if (sel == 0) {
          Qh[(long)tok * 1024 + col] = h;
        } else {
          Kh[(long)tok * 1024 + col] = h;
        }
      }
    }
  }
}

// Batched NT GEMM with fp32 output: C[z] = alpha * A[z] * B[z]^T
__global__ __launch_bounds__(256, 4) void gemm_f32out(
    const unsigned short* __restrict__ A, const unsigned short* __restrict__ B,
    int lda, int ldb, int K,
    long sA, long sB, float* __restrict__ C, int ldc, long sC, float alpha)
{
  __shared__ __align__(16) unsigned short ldsA[8192];
  __shared__ __align__(16) unsigned short ldsB[8192];
  const int Mblk = blockIdx.x * 128;
  const int Nblk = blockIdx.y * 128;
  const long z = blockIdx.z;
  const unsigned short* Ab = A + z * sA + (long)Mblk * lda;
  const unsigned short* Bb = B + z * sB + (long)Nblk * ldb;
  float* Cb = C + z * sC;

  f32x4 acc[4][4] = {};
  gemm_core(Ab, Bb, lda, ldb, K, ldsA, ldsB, acc);

  const int lane = threadIdx.x & 63, wave = threadIdx.x >> 6;
  const int wm = (wave >> 1) * 64, wn = (wave & 1) * 64;
  const int lrow = lane & 15, kq = lane >> 4;
#pragma unroll
  for (int i = 0; i < 4; ++i)
#pragma unroll
    for (int j = 0; j < 4; ++j)
#pragma unroll
      for (int r = 0; r < 4; ++r) {
        const int row = Mblk + wm + i * 16 + kq * 4 + r;
        const int col = Nblk + wn + j * 16 + lrow;
        Cb[(long)row * ldc + col] = alpha * acc[i][j][r];
      }
}

// Row softmax over 2048 entries, in place (fp32) + bf16 copy for the PV GEMM.
__global__ __launch_bounds__(256) void softmax_rows(
    float* __restrict__ S, unsigned short* __restrict__ Ph)
{
  __shared__ float red[4];
  const long row = blockIdx.x;
  float* rp = S + row * 2048;
  const int t = threadIdx.x;

  float x[8];
  *(float4*)&x[0] = reinterpret_cast<const float4*>(rp)[t];
  *(float4*)&x[4] = reinterpret_cast<const float4*>(rp)[t + 256];

  float m = x[0];
#pragma unroll
  for (int i = 1; i < 8; ++i) m = fmaxf(m, x[i]);
  for (int o = 32; o; o >>= 1) m = fmaxf(m, __shfl_xor(m, o, 64));
  if ((t & 63) == 0) red[t >> 6] = m;
  __syncthreads();
  m = fmaxf(fmaxf(red[0], red[1]), fmaxf(red[2], red[3]));
  __syncthreads();

  float s = 0.f;
#pragma unroll
  for (int i = 0; i < 8; ++i) { x[i] = __expf(x[i] - m); s += x[i]; }
  for (int o = 32; o; o >>= 1) s += __shfl_xor(s, o, 64);
  if ((t & 63) == 0) red[t >> 6] = s;
  __syncthreads();
  s = (red[0] + red[1]) + (red[2] + red[3]);
  const float inv = 1.0f / s;

#pragma unroll
  for (int i = 0; i < 8; ++i) x[i] *= inv;
  reinterpret_cast<float4*>(rp)[t]       = *(float4*)&x[0];
  reinterpret_cast<float4*>(rp)[t + 256] = *(float4*)&x[4];

  // packed bf16 P stores (2 x 8B instead of 8 x 2B)
  ushort4 p0, p1;
  p0.x = f2bf(x[0]); p0.y = f2bf(x[1]); p0.z = f2bf(x[2]); p0.w = f2bf(x[3]);
  p1.x = f2bf(x[4]); p1.y = f2bf(x[5]); p1.z = f2bf(x[6]); p1.w = f2bf(x[7]);
  const long b0 = row * 2048 + t * 4;
  *reinterpret_cast<ushort4*>(Ph + b0)        = p0;
  *reinterpret_cast<ushort4*>(Ph + b0 + 1024) = p1;
}

// One fused cast pass: x (2,097,152 float4) then Wq|Wk|Wv (262,144 float4 each).
__global__ __launch_bounds__(256) void to_bf16_all(
    const float* __restrict__ x,
    const float* __restrict__ Wq, const float* __restrict__ Wk,
    const float* __restrict__ Wv,
    unsigned short* __restrict__ xh, unsigned short* __restrict__ wh)
{
  const int stride = gridDim.x * 256;
  for (int i = blockIdx.x * 256 + threadIdx.x; i < 2883584; i += stride) {
    const float* src; unsigned short* dst; int off;
    if (i < 2097152)      { src = x;  dst = xh; off = i; }
    else {
      const int j = i - 2097152;
      const int sel = j >> 18;          // 0..2 (262144 float4 per W)
      off = j & 262143;
      src = (sel == 0) ? Wq : (sel == 1) ? Wk : Wv;
      dst = wh + (long)sel * 1048576;
    }
    const float4 v = reinterpret_cast<const float4*>(src)[off];
    ushort4 h;
    h.x = f2bf(v.x); h.y = f2bf(v.y); h.z = f2bf(v.z); h.w = f2bf(v.w);
    reinterpret_cast<ushort4*>(dst)[off] = h;
  }
}

extern "C" void kernel_launch(void* const* d_in, const int* in_sizes, int n_in,
                              void* d_out, int out_size, void* d_ws, size_t ws_size,
                              hipStream_t stream)
{
  const float* x  = (const float*)d_in[0];
  const float* Wq = (const float*)d_in[1];
  const float* bq = (const float*)d_in[2];
  const float* Wk = (const float*)d_in[3];
  const float* bk = (const float*)d_in[4];
  const float* Wv = (const float*)d_in[5];
  const float* bv = (const float*)d_in[6];

  float* out  = (float*)d_out;                 // [4,2048,1024]
  float* attn = (float*)d_out + 8388608;       // [4,2048,2048]

  unsigned short* ws  = (unsigned short*)d_ws;
  unsigned short* xh  = ws;                    //  8,388,608
  unsigned short* wh  = xh + 8388608;          //  3,145,728 (Wq|Wk|Wv)
  unsigned short* Qh  = wh + 3145728;          //  8,388,608
  unsigned short* Kh  = Qh + 8388608;          //  8,388,608
  unsigned short* Vth = Kh + 8388608;          //  8,388,608  Vt[b][d][m]
  unsigned short* Ph  = Vth + 8388608;         // 16,777,216  P bf16

  to_bf16_all<<<2048, 256, 0, stream>>>(x, Wq, Wk, Wv, xh, wh);

  // Q,K,V projections (M=8192, N=3x1024, K=1024)
  gemm_qkv<<<dim3(64, 24), 256, 0, stream>>>(xh, wh, bq, bk, bv, Qh, Kh, Vth);

  // scores = Q K^T / 32  -> fp32 straight into d_out's attention slot
  gemm_f32out<<<dim3(16, 16, 4), 256, 0, stream>>>(Qh, Kh, 1024, 1024, 1024,
      2097152L, 2097152L, attn, 2048, 4194304L, 0.03125f);

  // softmax rows in place + emit P bf16
  softmax_rows<<<8192, 256, 0, stream>>>(attn, Ph);

  // out = P * Vt^T
  gemm_f32out<<<dim3(16, 8, 4), 256, 0, stream>>>(Ph, Vth, 2048, 2048, 2048,
      4194304L, 2097152L, out, 1024, 2097152L, 1.0f);
}